// Round 8
// baseline (453.580 us; speedup 1.0000x reference)
//
#include <hip/hip_runtime.h>

// Problem constants
#define DIMX 256
#define NMX  32768   // N*M tokens per batch
#define TB   64      // tokens per tile
#define PITCH 544    // LDS row pitch in bytes (34*16B; bank-rotation 8/row)

typedef short s16x8 __attribute__((ext_vector_type(8)));  // 8 bf16 in 4 VGPRs
typedef float f32x4 __attribute__((ext_vector_type(4)));

// ws layout (bytes): packed bf16 A-fragments per matrix, then fp32 Wkv temp
#define OFF_WQN   (0u)        // -Wq  (K=256,E=256) 128KB
#define OFF_WK    (131072u)   //  Wk                128KB
#define OFF_WKV   (262144u)   //  Wk@Wv             128KB
#define OFF_W1    (393216u)   //  W1  (K=256,E=128)  64KB
#define OFF_W2    (458752u)   //  W2  (K=128,E=256)  64KB
#define OFF_WO    (524288u)   //  Wo                128KB
#define OFF_KVF32 (655360u)   //  fp32 Wkv temp     256KB

__device__ __forceinline__ ushort f2bf(float f) {
  uint u = __builtin_bit_cast(uint, f);
  return (ushort)((u + 0x7FFFu + ((u >> 16) & 1u)) >> 16);  // RNE
}
__device__ __forceinline__ uint cvtpk(float lo, float hi) {
  uint r;
  asm("v_cvt_pk_bf16_f32 %0, %1, %2" : "=v"(r) : "v"(lo), "v"(hi));
  return r;
}
__device__ __forceinline__ float bf_lo(uint u) {
  return __builtin_bit_cast(float, u << 16);
}
__device__ __forceinline__ float bf_hi(uint u) {
  return __builtin_bit_cast(float, u & 0xffff0000u);
}

// K0: Wkv = Wk @ Wv in fp32 (256x256x256, trivial)
__global__ void wkv_kernel(const float* __restrict__ Wk, const float* __restrict__ Wv,
                           float* __restrict__ outw) {
  const int e = threadIdx.x, d = blockIdx.x;
  float acc = 0.f;
  #pragma unroll 8
  for (int m = 0; m < DIMX; ++m) acc += Wk[d * DIMX + m] * Wv[m * DIMX + e];
  outw[d * DIMX + e] = acc;
}

// K1: pack all weights into MFMA 16x16x32 A-fragment order, bf16.
// A-frag for W(K x E) used as A = W^T: value[lane][j] = W[ks*32+(lane>>4)*8+j][r*16+(lane&15)]
// frag id = ks*(E/16)+r, stored at off + (frag*64+lane)*16 bytes.
__global__ void pack_kernel(const float* __restrict__ Wq, const float* __restrict__ Wk,
                            const float* __restrict__ Wkvf, const float* __restrict__ W1,
                            const float* __restrict__ W2, const float* __restrict__ Wo,
                            ushort* __restrict__ wsout) {
  const int fid = blockIdx.x, lane = threadIdx.x;  // 640 blocks x 64 threads
  const float* src; int Eout = 256; float sgn = 1.f; uint off; int local;
  if (fid < 128)      { src = Wq;   sgn = -1.f; off = OFF_WQN; local = fid;       }
  else if (fid < 256) { src = Wk;   off = OFF_WK;  local = fid - 128;             }
  else if (fid < 384) { src = Wkvf; off = OFF_WKV; local = fid - 256;             }
  else if (fid < 448) { src = W1;   Eout = 128; off = OFF_W1; local = fid - 384;  }
  else if (fid < 512) { src = W2;   off = OFF_W2;  local = fid - 448;             }
  else                { src = Wo;   off = OFF_WO;  local = fid - 512;             }
  const int R  = Eout >> 4;
  const int ks = local / R, r = local - ks * R;
  const int e  = r * 16 + (lane & 15);
  const int k0 = ks * 32 + (lane >> 4) * 8;
  union { uint4 u4; ushort us[8]; } o;
  #pragma unroll
  for (int j = 0; j < 8; ++j) o.us[j] = f2bf(sgn * src[(k0 + j) * Eout + e]);
  *(uint4*)((char*)wsout + off + (((uint)local * 64u + (uint)lane) * 16u)) = o.u4;
}

// Main fused kernel. 512 WGs; each WG loops over 4 consecutive 64-token tiles
// of one batch. 8 waves; wave w owns output rows [w*32, w*32+32) (rows
// [w*16,w*16+16) for the 128-wide hidden stage). LDS: ba 34KB (q->attn->x),
// bb 34KB (k->h); [t][d] bf16 pitch 544B + XOR swizzle ((t&7)<<4).
// Pipelining (T14): next tile's k loads issue under the W1 phase, q loads
// under the WO phase, into registers; at loop top staging is pure
// ds_write_b128 from regs — no HBM latency on the critical path.
#define MFMA16(A,B,C) __builtin_amdgcn_mfma_f32_16x16x32_bf16(A, B, C, 0, 0, 0)

__global__ __launch_bounds__(512, 4) void fused_main(
    const float* __restrict__ q, const float* __restrict__ kin,
    const float* __restrict__ pos, const int* __restrict__ mask,
    const float* __restrict__ b1, const float* __restrict__ b2,
    const float* __restrict__ bo, const ushort* __restrict__ wfr,
    float* __restrict__ out)
{
  __shared__ __align__(128) char ba[TB * PITCH];  // 34KB
  __shared__ __align__(128) char bb[TB * PITCH];  // 34KB
  const char* wb = (const char*)wfr;

  const int tid = threadIdx.x;
  const int w = tid >> 6, l = tid & 63;
  const int c = l & 15, g = l >> 4;
  const int b  = blockIdx.x >> 7;            // 128 strips per batch
  const int t0base = (blockIdx.x & 127) * 256;

  // B-fragment read: lane supplies B[k = ks*32 + g*8 + j][t = tf*16 + c]
  auto ldB = [&](const char* buf, int ks, int tf) -> s16x8 {
    const int t = (tf << 4) + c;
    const int col = (ks << 6) + (g << 4);
    return *(const s16x8*)(buf + t * PITCH + (col ^ ((t & 7) << 4)));
  };
  // A-fragment (weights) from packed global, 16B/lane
  auto ldA = [&](uint moff, int fi) -> s16x8 {
    return *(const s16x8*)(wb + moff + (((uint)fi << 6) | (uint)l) * 16u);
  };
  // write 4 consecutive-e bf16 values (packed lo,hi) at (e0, t)
  auto stW4 = [&](char* buf, int e0, int t, uint lo, uint hi) {
    const int byte = t * PITCH + (((uint)(e0 * 2)) ^ ((t & 7) << 4));
    *(uint2*)(buf + byte) = uint2{lo, hi};
  };

  uint qn[16], kn[16];   // next-tile staged data (packed bf16 pairs)

  #pragma unroll 1
  for (int it = 0; it < 4; ++it) {
    const int t0 = t0base + (it << 6);
    const size_t gbase = (size_t)b * DIMX * NMX + t0 + l;

    if (it == 0) {
      // ---- cold staging: q -> ba, k -> bb (transposed, bf16, swizzled) ----
      #pragma unroll
      for (int j4 = 0; j4 < 4; ++j4) {
        const int d0 = (w << 5) + (j4 << 3);
        uint pq[4], pk[4];
        #pragma unroll
        for (int p = 0; p < 4; ++p) {
          const size_t o0 = gbase + (size_t)(d0 + 2 * p) * NMX;
          const size_t o1 = o0 + NMX;
          pq[p] = cvtpk(__builtin_nontemporal_load(q + o0),
                        __builtin_nontemporal_load(q + o1));
          pk[p] = cvtpk(__builtin_nontemporal_load(kin + o0),
                        __builtin_nontemporal_load(kin + o1));
        }
        const int byte = l * PITCH + ((d0 << 1) ^ ((l & 7) << 4));
        *(uint4*)(ba + byte) = uint4{pq[0], pq[1], pq[2], pq[3]};
        *(uint4*)(bb + byte) = uint4{pk[0], pk[1], pk[2], pk[3]};
      }
    } else {
      // ---- warm staging: prefetched regs -> LDS (no global latency) ----
      #pragma unroll
      for (int j4 = 0; j4 < 4; ++j4) {
        const int d0 = (w << 5) + (j4 << 3);
        const int byte = l * PITCH + ((d0 << 1) ^ ((l & 7) << 4));
        *(uint4*)(ba + byte) = uint4{qn[4*j4], qn[4*j4+1], qn[4*j4+2], qn[4*j4+3]};
        *(uint4*)(bb + byte) = uint4{kn[4*j4], kn[4*j4+1], kn[4*j4+2], kn[4*j4+3]};
      }
    }

    // ---- pos + mask loads BEFORE the barrier (latency hides under it) ----
    f32x4 posr[4][2];
    {
      const float* pz = pos + ((size_t)b * NMX + t0) * DIMX;
      #pragma unroll
      for (int tf = 0; tf < 4; ++tf) {
        const int t = (tf << 4) + c;
        #pragma unroll
        for (int ef = 0; ef < 2; ++ef) {
          const int e0 = (w << 5) + (ef << 4) + (g << 2);
          posr[tf][ef] =
              __builtin_nontemporal_load((const f32x4*)(pz + (size_t)t * DIMX + e0));
        }
      }
    }
    int mk[4];
    #pragma unroll
    for (int tf = 0; tf < 4; ++tf)
      mk[tf] = mask[(size_t)b * NMX + t0 + (tf << 4) + c];

    __syncthreads();   // B1: tiles staged

    // pos -> bf16
    uint posbf[2][4][2];
    #pragma unroll
    for (int tf = 0; tf < 4; ++tf)
      #pragma unroll
      for (int ef = 0; ef < 2; ++ef) {
        posbf[ef][tf][0] = cvtpk(posr[tf][ef][0], posr[tf][ef][1]);
        posbf[ef][tf][1] = cvtpk(posr[tf][ef][2], posr[tf][ef][3]);
      }

    // ---- phase 2 (merged): av = Wkv^T k; aa = Wk^T k + (-Wq)^T q ----
    f32x4 av[2][4], aa[2][4];
    #pragma unroll
    for (int ef = 0; ef < 2; ++ef)
      #pragma unroll
      for (int tf = 0; tf < 4; ++tf) {
        av[ef][tf] = f32x4{0.f, 0.f, 0.f, 0.f};
        aa[ef][tf] = f32x4{0.f, 0.f, 0.f, 0.f};
      }
    #pragma unroll 2
    for (int ks = 0; ks < 8; ++ks) {
      const s16x8 v0 = ldA(OFF_WKV, (ks << 4) + (w << 1));
      const s16x8 v1 = ldA(OFF_WKV, (ks << 4) + (w << 1) + 1);
      const s16x8 k0 = ldA(OFF_WK,  (ks << 4) + (w << 1));
      const s16x8 k1 = ldA(OFF_WK,  (ks << 4) + (w << 1) + 1);
      const s16x8 a0 = ldA(OFF_WQN, (ks << 4) + (w << 1));
      const s16x8 a1 = ldA(OFF_WQN, (ks << 4) + (w << 1) + 1);
      #pragma unroll
      for (int tf = 0; tf < 4; ++tf) {
        const s16x8 bk = ldB(bb, ks, tf);
        const s16x8 bq = ldB(ba, ks, tf);
        av[0][tf] = MFMA16(v0, bk, av[0][tf]);
        av[1][tf] = MFMA16(v1, bk, av[1][tf]);
        aa[0][tf] = MFMA16(k0, bk, aa[0][tf]);
        aa[1][tf] = MFMA16(k1, bk, aa[1][tf]);
        aa[0][tf] = MFMA16(a0, bq, aa[0][tf]);
        aa[1][tf] = MFMA16(a1, bq, aa[1][tf]);
      }
    }
    // pack v to bf16 (av dies)
    uint vbf[2][4][2];
    #pragma unroll
    for (int ef = 0; ef < 2; ++ef)
      #pragma unroll
      for (int tf = 0; tf < 4; ++tf) {
        vbf[ef][tf][0] = cvtpk(av[ef][tf][0], av[ef][tf][1]);
        vbf[ef][tf][1] = cvtpk(av[ef][tf][2], av[ef][tf][3]);
      }
    __syncthreads();   // B2: q,k consumption done

    // ---- attn = aa + pos -> bf16 -> ba rows [w*32,+32) ----
    #pragma unroll
    for (int tf = 0; tf < 4; ++tf) {
      const int t = (tf << 4) + c;
      #pragma unroll
      for (int ef = 0; ef < 2; ++ef) {
        const int e0 = (w << 5) + (ef << 4) + (g << 2);
        const uint p0 = posbf[ef][tf][0], p1 = posbf[ef][tf][1];
        const uint lo = cvtpk(aa[ef][tf][0] + bf_lo(p0), aa[ef][tf][1] + bf_hi(p0));
        const uint hi = cvtpk(aa[ef][tf][2] + bf_lo(p1), aa[ef][tf][3] + bf_hi(p1));
        stW4(ba, e0, t, lo, hi);
      }
    }
    __syncthreads();   // B3: attn tile complete

    // ---- phase 5: h = relu(W1^T attn + b1) -> bb rows [w*16,+16) ----
    // next-tile k prefetch issues first; its latency hides under the MFMAs.
    float kf[32];
    if (it < 3) {
      #pragma unroll
      for (int j4 = 0; j4 < 4; ++j4) {
        const int d0 = (w << 5) + (j4 << 3);
        #pragma unroll
        for (int p = 0; p < 4; ++p) {
          const size_t o0 = gbase + 64 + (size_t)(d0 + 2 * p) * NMX;
          kf[j4 * 8 + 2 * p]     = __builtin_nontemporal_load(kin + o0);
          kf[j4 * 8 + 2 * p + 1] = __builtin_nontemporal_load(kin + o0 + NMX);
        }
      }
    }
    f32x4 ah[4];
    #pragma unroll
    for (int tf = 0; tf < 4; ++tf) ah[tf] = f32x4{0.f, 0.f, 0.f, 0.f};
    #pragma unroll 2
    for (int ks = 0; ks < 8; ++ks) {
      const s16x8 a0 = ldA(OFF_W1, (ks << 3) + w);
      #pragma unroll
      for (int tf = 0; tf < 4; ++tf) {
        const s16x8 bf = ldB(ba, ks, tf);
        ah[tf] = MFMA16(a0, bf, ah[tf]);
      }
    }
    if (it < 3) {
      #pragma unroll
      for (int i = 0; i < 16; ++i) kn[i] = cvtpk(kf[2 * i], kf[2 * i + 1]);
    }
    {
      const int e0h = (w << 4) + (g << 2);
      const f32x4 b1v = *(const f32x4*)(b1 + e0h);
      #pragma unroll
      for (int tf = 0; tf < 4; ++tf) {
        const int t = (tf << 4) + c;
        const uint lo = cvtpk(fmaxf(ah[tf][0] + b1v[0], 0.f),
                              fmaxf(ah[tf][1] + b1v[1], 0.f));
        const uint hi = cvtpk(fmaxf(ah[tf][2] + b1v[2], 0.f),
                              fmaxf(ah[tf][3] + b1v[3], 0.f));
        stW4(bb, e0h, t, lo, hi);
      }
    }
    __syncthreads();   // B4: h tile complete

    // ---- phase 6: a2 = W2^T h + b2; mask; sigmoid; x = (v+pos)*sig -> ba ----
    f32x4 as_[2][4];
    #pragma unroll
    for (int ef = 0; ef < 2; ++ef)
      #pragma unroll
      for (int tf = 0; tf < 4; ++tf) as_[ef][tf] = f32x4{0.f, 0.f, 0.f, 0.f};
    #pragma unroll
    for (int ks = 0; ks < 4; ++ks) {
      const s16x8 a0 = ldA(OFF_W2, (ks << 4) + (w << 1));
      const s16x8 a1 = ldA(OFF_W2, (ks << 4) + (w << 1) + 1);
      #pragma unroll
      for (int tf = 0; tf < 4; ++tf) {
        const s16x8 bf = ldB(bb, ks, tf);
        as_[0][tf] = MFMA16(a0, bf, as_[0][tf]);
        as_[1][tf] = MFMA16(a1, bf, as_[1][tf]);
      }
    }
    #pragma unroll
    for (int tf = 0; tf < 4; ++tf) {
      const int t = (tf << 4) + c;
      #pragma unroll
      for (int ef = 0; ef < 2; ++ef) {
        const int e0 = (w << 5) + (ef << 4) + (g << 2);
        const f32x4 b2v = *(const f32x4*)(b2 + e0);
        float xv[4];
        #pragma unroll
        for (int i = 0; i < 4; ++i) {
          float sv = as_[ef][tf][i] + b2v[i];
          if (mk[tf] == 0) sv = -1e9f;
          const float sig = 1.f / (1.f + __expf(-sv));
          const uint pv = vbf[ef][tf][i >> 1];
          const uint pp = posbf[ef][tf][i >> 1];
          const float vv = (i & 1) ? bf_hi(pv) : bf_lo(pv);
          const float pf = (i & 1) ? bf_hi(pp) : bf_lo(pp);
          xv[i] = (vv + pf) * sig;
        }
        stW4(ba, e0, t, cvtpk(xv[0], xv[1]), cvtpk(xv[2], xv[3]));
      }
    }
    __syncthreads();   // B5: x tile complete

    // ---- phase 7: out = Wo^T x + bo; next-tile q prefetch under MFMAs ----
    float qf[32];
    if (it < 3) {
      #pragma unroll
      for (int j4 = 0; j4 < 4; ++j4) {
        const int d0 = (w << 5) + (j4 << 3);
        #pragma unroll
        for (int p = 0; p < 4; ++p) {
          const size_t o0 = gbase + 64 + (size_t)(d0 + 2 * p) * NMX;
          qf[j4 * 8 + 2 * p]     = __builtin_nontemporal_load(q + o0);
          qf[j4 * 8 + 2 * p + 1] = __builtin_nontemporal_load(q + o0 + NMX);
        }
      }
    }
    f32x4 ao[2][4];
    #pragma unroll
    for (int ef = 0; ef < 2; ++ef)
      #pragma unroll
      for (int tf = 0; tf < 4; ++tf) ao[ef][tf] = f32x4{0.f, 0.f, 0.f, 0.f};
    #pragma unroll 2
    for (int ks = 0; ks < 8; ++ks) {
      const s16x8 a0 = ldA(OFF_WO, (ks << 4) + (w << 1));
      const s16x8 a1 = ldA(OFF_WO, (ks << 4) + (w << 1) + 1);
      #pragma unroll
      for (int tf = 0; tf < 4; ++tf) {
        const s16x8 bf = ldB(ba, ks, tf);
        ao[0][tf] = MFMA16(a0, bf, ao[0][tf]);
        ao[1][tf] = MFMA16(a1, bf, ao[1][tf]);
      }
    }
    if (it < 3) {
      #pragma unroll
      for (int i = 0; i < 16; ++i) qn[i] = cvtpk(qf[2 * i], qf[2 * i + 1]);
    }
    #pragma unroll
    for (int ef = 0; ef < 2; ++ef) {
      const int e0 = (w << 5) + (ef << 4) + (g << 2);
      const f32x4 bov = *(const f32x4*)(bo + e0);
      #pragma unroll
      for (int i = 0; i < 4; ++i) {
        float* ob = out + ((size_t)b * DIMX + e0 + i) * NMX + t0 + c;
        #pragma unroll
        for (int tf = 0; tf < 4; ++tf)
          ob[tf << 4] = ao[ef][tf][i] + bov[i];
      }
    }
    if (it < 3) __syncthreads();   // B6: x reads done -> safe to restage
  }
}

extern "C" void kernel_launch(void* const* d_in, const int* in_sizes, int n_in,
                              void* d_out, int out_size, void* d_ws, size_t ws_size,
                              hipStream_t stream) {
  (void)in_sizes; (void)n_in; (void)out_size; (void)ws_size;
  const float* q   = (const float*)d_in[0];
  const float* k   = (const float*)d_in[1];
  const float* pos = (const float*)d_in[2];
  const int*   msk = (const int*)d_in[3];
  const float* Wq  = (const float*)d_in[4];
  const float* Wk  = (const float*)d_in[5];
  const float* Wv  = (const float*)d_in[6];
  const float* W1  = (const float*)d_in[7];
  const float* b1  = (const float*)d_in[8];
  const float* W2  = (const float*)d_in[9];
  const float* b2  = (const float*)d_in[10];
  const float* Wo  = (const float*)d_in[11];
  const float* bo  = (const float*)d_in[12];
  float* out = (float*)d_out;
  char* ws = (char*)d_ws;
  float*  wkvf = (float*)(ws + OFF_KVF32);
  ushort* wfr  = (ushort*)ws;

  wkv_kernel<<<dim3(256), dim3(256), 0, stream>>>(Wk, Wv, wkvf);
  pack_kernel<<<dim3(640), dim3(64), 0, stream>>>(Wq, Wk, wkvf, W1, W2, Wo, wfr);
  fused_main<<<dim3(512), dim3(512), 0, stream>>>(q, k, pos, msk, b1, b2, bo, wfr, out);
}

// Round 9
// 175.064 us; speedup vs baseline: 2.5909x; 2.5909x over previous
//
#include <hip/hip_runtime.h>

// Problem constants
#define DIMX 256
#define NMX  32768   // N*M tokens per batch
#define TB   64      // tokens per workgroup
#define PITCH 544    // LDS row pitch in bytes (34*16B; bank-rotation 8/row)

typedef short s16x8 __attribute__((ext_vector_type(8)));  // 8 bf16 in 4 VGPRs
typedef float f32x4 __attribute__((ext_vector_type(4)));

// ws layout (bytes): packed bf16 A-fragments per matrix, then fp32 Wkv temp
#define OFF_WQN   (0u)        // -Wq  (K=256,E=256) 128KB
#define OFF_WK    (131072u)   //  Wk                128KB
#define OFF_WKV   (262144u)   //  Wk@Wv             128KB
#define OFF_W1    (393216u)   //  W1  (K=256,E=128)  64KB
#define OFF_W2    (458752u)   //  W2  (K=128,E=256)  64KB
#define OFF_WO    (524288u)   //  Wo                128KB
#define OFF_KVF32 (655360u)   //  fp32 Wkv temp     256KB

__device__ __forceinline__ ushort f2bf(float f) {
  uint u = __builtin_bit_cast(uint, f);
  return (ushort)((u + 0x7FFFu + ((u >> 16) & 1u)) >> 16);  // RNE
}
__device__ __forceinline__ uint cvtpk(float lo, float hi) {
  uint r;
  asm("v_cvt_pk_bf16_f32 %0, %1, %2" : "=v"(r) : "v"(lo), "v"(hi));
  return r;
}
__device__ __forceinline__ float bf_lo(uint u) {
  return __builtin_bit_cast(float, u << 16);
}
__device__ __forceinline__ float bf_hi(uint u) {
  return __builtin_bit_cast(float, u & 0xffff0000u);
}

// K0: Wkv = Wk @ Wv in fp32 (256x256x256, trivial)
__global__ void wkv_kernel(const float* __restrict__ Wk, const float* __restrict__ Wv,
                           float* __restrict__ outw) {
  const int e = threadIdx.x, d = blockIdx.x;
  float acc = 0.f;
  #pragma unroll 8
  for (int m = 0; m < DIMX; ++m) acc += Wk[d * DIMX + m] * Wv[m * DIMX + e];
  outw[d * DIMX + e] = acc;
}

// K1: pack all weights into MFMA 16x16x32 A-fragment order, bf16.
// A-frag for W(K x E) used as A = W^T: value[lane][j] = W[ks*32+(lane>>4)*8+j][r*16+(lane&15)]
// frag id = ks*(E/16)+r, stored at off + (frag*64+lane)*16 bytes.
__global__ void pack_kernel(const float* __restrict__ Wq, const float* __restrict__ Wk,
                            const float* __restrict__ Wkvf, const float* __restrict__ W1,
                            const float* __restrict__ W2, const float* __restrict__ Wo,
                            ushort* __restrict__ wsout) {
  const int fid = blockIdx.x, lane = threadIdx.x;  // 640 blocks x 64 threads
  const float* src; int Eout = 256; float sgn = 1.f; uint off; int local;
  if (fid < 128)      { src = Wq;   sgn = -1.f; off = OFF_WQN; local = fid;       }
  else if (fid < 256) { src = Wk;   off = OFF_WK;  local = fid - 128;             }
  else if (fid < 384) { src = Wkvf; off = OFF_WKV; local = fid - 256;             }
  else if (fid < 448) { src = W1;   Eout = 128; off = OFF_W1; local = fid - 384;  }
  else if (fid < 512) { src = W2;   off = OFF_W2;  local = fid - 448;             }
  else                { src = Wo;   off = OFF_WO;  local = fid - 512;             }
  const int R  = Eout >> 4;
  const int ks = local / R, r = local - ks * R;
  const int e  = r * 16 + (lane & 15);
  const int k0 = ks * 32 + (lane >> 4) * 8;
  union { uint4 u4; ushort us[8]; } o;
  #pragma unroll
  for (int j = 0; j < 8; ++j) o.us[j] = f2bf(sgn * src[(k0 + j) * Eout + e]);
  *(uint4*)((char*)wsout + off + (((uint)local * 64u + (uint)lane) * 16u)) = o.u4;
}

// Main fused kernel (r5 champion + register-neutral tweaks).
// WG = 64 tokens of one batch, 8 waves; wave w owns output rows [w*32,+32)
// (rows [w*16,+16) for the 128-wide hidden stage).
// LDS: ba 34KB (q -> attn -> x), bb 34KB (k -> h); [t][d] bf16 pitch 544B +
// XOR swizzle ((t&7)<<4). pos/mask VMEM issued FIRST so the pre-B1 drain
// overlaps them; setprio(1) around MFMA clusters (T5); v+pos pre-fused to
// bf16 while both are live (phase-6 VALU shrink).
#define MFMA16(A,B,C) __builtin_amdgcn_mfma_f32_16x16x32_bf16(A, B, C, 0, 0, 0)

__global__ __launch_bounds__(512, 4) void fused_main(
    const float* __restrict__ q, const float* __restrict__ kin,
    const float* __restrict__ pos, const int* __restrict__ mask,
    const float* __restrict__ b1, const float* __restrict__ b2,
    const float* __restrict__ bo, const ushort* __restrict__ wfr,
    float* __restrict__ out)
{
  __shared__ __align__(128) char ba[TB * PITCH];  // 34KB
  __shared__ __align__(128) char bb[TB * PITCH];  // 34KB
  const char* wb = (const char*)wfr;

  const int tid = threadIdx.x;
  const int w = tid >> 6, l = tid & 63;
  const int c = l & 15, g = l >> 4;
  const int b  = blockIdx.x >> 9;           // 512 token-blocks per batch
  const int t0 = (blockIdx.x & 511) * TB;

  // B-fragment read: lane supplies B[k = ks*32 + g*8 + j][t = tf*16 + c]
  auto ldB = [&](const char* buf, int ks, int tf) -> s16x8 {
    const int t = (tf << 4) + c;
    const int col = (ks << 6) + (g << 4);
    return *(const s16x8*)(buf + t * PITCH + (col ^ ((t & 7) << 4)));
  };
  // A-fragment (weights) from packed global, 16B/lane
  auto ldA = [&](uint moff, int fi) -> s16x8 {
    return *(const s16x8*)(wb + moff + (((uint)fi << 6) | (uint)l) * 16u);
  };
  // write 4 consecutive-e bf16 values (packed lo,hi) at (e0, t)
  auto stW4 = [&](char* buf, int e0, int t, uint lo, uint hi) {
    const int byte = t * PITCH + (((uint)(e0 * 2)) ^ ((t & 7) << 4));
    *(uint2*)(buf + byte) = uint2{lo, hi};
  };

  const size_t gbase = (size_t)b * DIMX * NMX + t0 + l;

  // ---- pos + mask VMEM first: they drain concurrently with staging loads ----
  f32x4 posr[4][2];
  {
    const float* pz = pos + ((size_t)b * NMX + t0) * DIMX;
    #pragma unroll
    for (int tf = 0; tf < 4; ++tf) {
      const int t = (tf << 4) + c;
      #pragma unroll
      for (int ef = 0; ef < 2; ++ef) {
        const int e0 = (w << 5) + (ef << 4) + (g << 2);
        posr[tf][ef] =
            __builtin_nontemporal_load((const f32x4*)(pz + (size_t)t * DIMX + e0));
      }
    }
  }
  int mk[4];
  #pragma unroll
  for (int tf = 0; tf < 4; ++tf)
    mk[tf] = mask[(size_t)b * NMX + t0 + (tf << 4) + c];

  // ---- stage q -> ba, k -> bb (transposed, bf16, swizzled); nt loads ----
  #pragma unroll
  for (int j4 = 0; j4 < 4; ++j4) {
    const int d0 = (w << 5) + (j4 << 3);
    uint pq[4], pk[4];
    #pragma unroll
    for (int p = 0; p < 4; ++p) {
      const size_t o0 = gbase + (size_t)(d0 + 2 * p) * NMX;
      const size_t o1 = o0 + NMX;
      pq[p] = cvtpk(__builtin_nontemporal_load(q + o0),
                    __builtin_nontemporal_load(q + o1));
      pk[p] = cvtpk(__builtin_nontemporal_load(kin + o0),
                    __builtin_nontemporal_load(kin + o1));
    }
    const int byte = l * PITCH + ((d0 << 1) ^ ((l & 7) << 4));
    *(uint4*)(ba + byte) = uint4{pq[0], pq[1], pq[2], pq[3]};
    *(uint4*)(bb + byte) = uint4{pk[0], pk[1], pk[2], pk[3]};
  }

  __syncthreads();   // B1: tiles staged (drain covered pos/mask too)

  // pos -> bf16 (frees posr)
  uint posbf[2][4][2];
  #pragma unroll
  for (int tf = 0; tf < 4; ++tf)
    #pragma unroll
    for (int ef = 0; ef < 2; ++ef) {
      posbf[ef][tf][0] = cvtpk(posr[tf][ef][0], posr[tf][ef][1]);
      posbf[ef][tf][1] = cvtpk(posr[tf][ef][2], posr[tf][ef][3]);
    }

  // ---- phase 2ab (fused): av = Wkv^T k, aa = Wk^T k — shared B-fragments ----
  f32x4 av[2][4], aa[2][4];
  #pragma unroll
  for (int ef = 0; ef < 2; ++ef)
    #pragma unroll
    for (int tf = 0; tf < 4; ++tf) {
      av[ef][tf] = f32x4{0.f, 0.f, 0.f, 0.f};
      aa[ef][tf] = f32x4{0.f, 0.f, 0.f, 0.f};
    }
  __builtin_amdgcn_s_setprio(1);
  #pragma unroll 2
  for (int ks = 0; ks < 8; ++ks) {
    const s16x8 v0 = ldA(OFF_WKV, (ks << 4) + (w << 1));
    const s16x8 v1 = ldA(OFF_WKV, (ks << 4) + (w << 1) + 1);
    const s16x8 k0 = ldA(OFF_WK,  (ks << 4) + (w << 1));
    const s16x8 k1 = ldA(OFF_WK,  (ks << 4) + (w << 1) + 1);
    #pragma unroll
    for (int tf = 0; tf < 4; ++tf) {
      const s16x8 bf = ldB(bb, ks, tf);
      av[0][tf] = MFMA16(v0, bf, av[0][tf]);
      av[1][tf] = MFMA16(v1, bf, av[1][tf]);
      aa[0][tf] = MFMA16(k0, bf, aa[0][tf]);
      aa[1][tf] = MFMA16(k1, bf, aa[1][tf]);
    }
  }
  __builtin_amdgcn_s_setprio(0);
  // pre-fuse x-base = v + pos, pack to bf16 (av dies; register-neutral vs vbf)
  uint vpbf[2][4][2];
  #pragma unroll
  for (int ef = 0; ef < 2; ++ef)
    #pragma unroll
    for (int tf = 0; tf < 4; ++tf) {
      const uint p0 = posbf[ef][tf][0], p1 = posbf[ef][tf][1];
      vpbf[ef][tf][0] = cvtpk(av[ef][tf][0] + bf_lo(p0), av[ef][tf][1] + bf_hi(p0));
      vpbf[ef][tf][1] = cvtpk(av[ef][tf][2] + bf_lo(p1), av[ef][tf][3] + bf_hi(p1));
    }

  // ---- phase 2c: aa += (-Wq)^T q ----
  __builtin_amdgcn_s_setprio(1);
  #pragma unroll 2
  for (int ks = 0; ks < 8; ++ks) {
    const s16x8 a0 = ldA(OFF_WQN, (ks << 4) + (w << 1));
    const s16x8 a1 = ldA(OFF_WQN, (ks << 4) + (w << 1) + 1);
    #pragma unroll
    for (int tf = 0; tf < 4; ++tf) {
      const s16x8 bf = ldB(ba, ks, tf);
      aa[0][tf] = MFMA16(a0, bf, aa[0][tf]);
      aa[1][tf] = MFMA16(a1, bf, aa[1][tf]);
    }
  }
  __builtin_amdgcn_s_setprio(0);
  __syncthreads();   // B2: q,k consumption done

  // ---- attn = aa + pos -> bf16 -> ba rows [w*32,+32) ----
  #pragma unroll
  for (int tf = 0; tf < 4; ++tf) {
    const int t = (tf << 4) + c;
    #pragma unroll
    for (int ef = 0; ef < 2; ++ef) {
      const int e0 = (w << 5) + (ef << 4) + (g << 2);
      const uint p0 = posbf[ef][tf][0], p1 = posbf[ef][tf][1];
      const uint lo = cvtpk(aa[ef][tf][0] + bf_lo(p0), aa[ef][tf][1] + bf_hi(p0));
      const uint hi = cvtpk(aa[ef][tf][2] + bf_lo(p1), aa[ef][tf][3] + bf_hi(p1));
      stW4(ba, e0, t, lo, hi);
    }
  }
  __syncthreads();   // B3: attn tile complete

  // ---- phase 5: h = relu(W1^T attn + b1) -> bb rows [w*16,+16) ----
  f32x4 ah[4];
  #pragma unroll
  for (int tf = 0; tf < 4; ++tf) ah[tf] = f32x4{0.f, 0.f, 0.f, 0.f};
  __builtin_amdgcn_s_setprio(1);
  #pragma unroll 2
  for (int ks = 0; ks < 8; ++ks) {
    const s16x8 a0 = ldA(OFF_W1, (ks << 3) + w);
    #pragma unroll
    for (int tf = 0; tf < 4; ++tf) {
      const s16x8 bf = ldB(ba, ks, tf);
      ah[tf] = MFMA16(a0, bf, ah[tf]);
    }
  }
  __builtin_amdgcn_s_setprio(0);
  {
    const int e0h = (w << 4) + (g << 2);
    const f32x4 b1v = *(const f32x4*)(b1 + e0h);
    #pragma unroll
    for (int tf = 0; tf < 4; ++tf) {
      const int t = (tf << 4) + c;
      const uint lo = cvtpk(fmaxf(ah[tf][0] + b1v[0], 0.f),
                            fmaxf(ah[tf][1] + b1v[1], 0.f));
      const uint hi = cvtpk(fmaxf(ah[tf][2] + b1v[2], 0.f),
                            fmaxf(ah[tf][3] + b1v[3], 0.f));
      stW4(bb, e0h, t, lo, hi);
    }
  }
  __syncthreads();   // B4: h tile complete

  // ---- phase 6: a2 = W2^T h + b2; mask; sigmoid; x = (v+pos)*sig -> ba ----
  f32x4 as_[2][4];
  #pragma unroll
  for (int ef = 0; ef < 2; ++ef)
    #pragma unroll
    for (int tf = 0; tf < 4; ++tf) as_[ef][tf] = f32x4{0.f, 0.f, 0.f, 0.f};
  __builtin_amdgcn_s_setprio(1);
  #pragma unroll
  for (int ks = 0; ks < 4; ++ks) {
    const s16x8 a0 = ldA(OFF_W2, (ks << 4) + (w << 1));
    const s16x8 a1 = ldA(OFF_W2, (ks << 4) + (w << 1) + 1);
    #pragma unroll
    for (int tf = 0; tf < 4; ++tf) {
      const s16x8 bf = ldB(bb, ks, tf);
      as_[0][tf] = MFMA16(a0, bf, as_[0][tf]);
      as_[1][tf] = MFMA16(a1, bf, as_[1][tf]);
    }
  }
  __builtin_amdgcn_s_setprio(0);
  #pragma unroll
  for (int tf = 0; tf < 4; ++tf) {
    const int t = (tf << 4) + c;
    #pragma unroll
    for (int ef = 0; ef < 2; ++ef) {
      const int e0 = (w << 5) + (ef << 4) + (g << 2);
      const f32x4 b2v = *(const f32x4*)(b2 + e0);
      float xv[4];
      #pragma unroll
      for (int i = 0; i < 4; ++i) {
        float sv = as_[ef][tf][i] + b2v[i];
        if (mk[tf] == 0) sv = -1e9f;
        const float sig = 1.f / (1.f + __expf(-sv));
        const uint vp = vpbf[ef][tf][i >> 1];
        const float xb = (i & 1) ? bf_hi(vp) : bf_lo(vp);
        xv[i] = xb * sig;
      }
      stW4(ba, e0, t, cvtpk(xv[0], xv[1]), cvtpk(xv[2], xv[3]));
    }
  }
  __syncthreads();   // B5: x tile complete

  // ---- phase 7: out = Wo^T x + bo -> (B, D, N, M) ----
  f32x4 ao[2][4];
  #pragma unroll
  for (int ef = 0; ef < 2; ++ef)
    #pragma unroll
    for (int tf = 0; tf < 4; ++tf) ao[ef][tf] = f32x4{0.f, 0.f, 0.f, 0.f};
  __builtin_amdgcn_s_setprio(1);
  #pragma unroll 2
  for (int ks = 0; ks < 8; ++ks) {
    const s16x8 a0 = ldA(OFF_WO, (ks << 4) + (w << 1));
    const s16x8 a1 = ldA(OFF_WO, (ks << 4) + (w << 1) + 1);
    #pragma unroll
    for (int tf = 0; tf < 4; ++tf) {
      const s16x8 bf = ldB(ba, ks, tf);
      ao[0][tf] = MFMA16(a0, bf, ao[0][tf]);
      ao[1][tf] = MFMA16(a1, bf, ao[1][tf]);
    }
  }
  __builtin_amdgcn_s_setprio(0);
  #pragma unroll
  for (int ef = 0; ef < 2; ++ef) {
    const int e0 = (w << 5) + (ef << 4) + (g << 2);
    const f32x4 bov = *(const f32x4*)(bo + e0);
    #pragma unroll
    for (int i = 0; i < 4; ++i) {
      float* ob = out + ((size_t)b * DIMX + e0 + i) * NMX + t0 + c;
      #pragma unroll
      for (int tf = 0; tf < 4; ++tf)
        ob[tf << 4] = ao[ef][tf][i] + bov[i];
    }
  }
}

extern "C" void kernel_launch(void* const* d_in, const int* in_sizes, int n_in,
                              void* d_out, int out_size, void* d_ws, size_t ws_size,
                              hipStream_t stream) {
  (void)in_sizes; (void)n_in; (void)out_size; (void)ws_size;
  const float* q   = (const float*)d_in[0];
  const float* k   = (const float*)d_in[1];
  const float* pos = (const float*)d_in[2];
  const int*   msk = (const int*)d_in[3];
  const float* Wq  = (const float*)d_in[4];
  const float* Wk  = (const float*)d_in[5];
  const float* Wv  = (const float*)d_in[6];
  const float* W1  = (const float*)d_in[7];
  const float* b1  = (const float*)d_in[8];
  const float* W2  = (const float*)d_in[9];
  const float* b2  = (const float*)d_in[10];
  const float* Wo  = (const float*)d_in[11];
  const float* bo  = (const float*)d_in[12];
  float* out = (float*)d_out;
  char* ws = (char*)d_ws;
  float*  wkvf = (float*)(ws + OFF_KVF32);
  ushort* wfr  = (ushort*)ws;

  wkv_kernel<<<dim3(256), dim3(256), 0, stream>>>(Wk, Wv, wkvf);
  pack_kernel<<<dim3(640), dim3(64), 0, stream>>>(Wq, Wk, wkvf, W1, W2, Wo, wfr);
  fused_main<<<dim3(2048), dim3(512), 0, stream>>>(q, k, pos, msk, b1, b2, bo, wfr, out);
}

// Round 10
// 166.785 us; speedup vs baseline: 2.7196x; 1.0496x over previous
//
#include <hip/hip_runtime.h>

// Problem constants
#define DIMX 256
#define NMX  32768   // N*M tokens per batch
#define TB   64      // tokens per workgroup
#define PITCH 544    // LDS row pitch in bytes (34*16B; bank-rotation 8/row)

typedef short s16x8 __attribute__((ext_vector_type(8)));  // 8 bf16 in 4 VGPRs
typedef float f32x4 __attribute__((ext_vector_type(4)));

// ws layout (bytes): packed bf16 A-fragments per matrix, then fp32 Wkv temp
#define OFF_WQN   (0u)        // -Wq  (K=256,E=256) 128KB
#define OFF_WK    (131072u)   //  Wk                128KB
#define OFF_WKV   (262144u)   //  Wk@Wv             128KB
#define OFF_W1    (393216u)   //  W1  (K=256,E=128)  64KB
#define OFF_W2    (458752u)   //  W2  (K=128,E=256)  64KB
#define OFF_WO    (524288u)   //  Wo                128KB
#define OFF_KVF32 (655360u)   //  fp32 Wkv temp     256KB

__device__ __forceinline__ ushort f2bf(float f) {
  uint u = __builtin_bit_cast(uint, f);
  return (ushort)((u + 0x7FFFu + ((u >> 16) & 1u)) >> 16);  // RNE
}
__device__ __forceinline__ uint cvtpk(float lo, float hi) {
  uint r;
  asm("v_cvt_pk_bf16_f32 %0, %1, %2" : "=v"(r) : "v"(lo), "v"(hi));
  return r;
}
__device__ __forceinline__ float bf_lo(uint u) {
  return __builtin_bit_cast(float, u << 16);
}
__device__ __forceinline__ float bf_hi(uint u) {
  return __builtin_bit_cast(float, u & 0xffff0000u);
}

// K0: Wkv = Wk @ Wv in fp32 (256x256x256, trivial)
__global__ void wkv_kernel(const float* __restrict__ Wk, const float* __restrict__ Wv,
                           float* __restrict__ outw) {
  const int e = threadIdx.x, d = blockIdx.x;
  float acc = 0.f;
  #pragma unroll 8
  for (int m = 0; m < DIMX; ++m) acc += Wk[d * DIMX + m] * Wv[m * DIMX + e];
  outw[d * DIMX + e] = acc;
}

// K1: pack all weights into MFMA 16x16x32 A-fragment order, bf16.
// A-frag for W(K x E) used as A = W^T: value[lane][j] = W[ks*32+(lane>>4)*8+j][r*16+(lane&15)]
// frag id = ks*(E/16)+r, stored at off + (frag*64+lane)*16 bytes.
__global__ void pack_kernel(const float* __restrict__ Wq, const float* __restrict__ Wk,
                            const float* __restrict__ Wkvf, const float* __restrict__ W1,
                            const float* __restrict__ W2, const float* __restrict__ Wo,
                            ushort* __restrict__ wsout) {
  const int fid = blockIdx.x, lane = threadIdx.x;  // 640 blocks x 64 threads
  const float* src; int Eout = 256; float sgn = 1.f; uint off; int local;
  if (fid < 128)      { src = Wq;   sgn = -1.f; off = OFF_WQN; local = fid;       }
  else if (fid < 256) { src = Wk;   off = OFF_WK;  local = fid - 128;             }
  else if (fid < 384) { src = Wkvf; off = OFF_WKV; local = fid - 256;             }
  else if (fid < 448) { src = W1;   Eout = 128; off = OFF_W1; local = fid - 384;  }
  else if (fid < 512) { src = W2;   off = OFF_W2;  local = fid - 448;             }
  else                { src = Wo;   off = OFF_WO;  local = fid - 512;             }
  const int R  = Eout >> 4;
  const int ks = local / R, r = local - ks * R;
  const int e  = r * 16 + (lane & 15);
  const int k0 = ks * 32 + (lane >> 4) * 8;
  union { uint4 u4; ushort us[8]; } o;
  #pragma unroll
  for (int j = 0; j < 8; ++j) o.us[j] = f2bf(sgn * src[(k0 + j) * Eout + e]);
  *(uint4*)((char*)wsout + off + (((uint)local * 64u + (uint)lane) * 16u)) = o.u4;
}

// Main fused kernel (r9 champion + merged phase-2 + nt out stores).
// WG = 64 tokens of one batch, 8 waves; wave w owns output rows [w*32,+32)
// (rows [w*16,+16) for the 128-wide hidden stage).
// LDS: ba 34KB (q -> attn -> x), bb 34KB (k -> h); [t][d] bf16 pitch 544B +
// XOR swizzle ((t&7)<<4). pos/mask VMEM issued FIRST so the pre-B1 drain
// overlaps them; setprio(1) around MFMA clusters (T5); v+pos pre-fused to
// bf16 while both are live. Phase 2 is ONE ks-loop (unroll 1): 6 A-frags,
// both B-buffers, 24 MFMAs per iteration — halves exposed ldA chain starts.
#define MFMA16(A,B,C) __builtin_amdgcn_mfma_f32_16x16x32_bf16(A, B, C, 0, 0, 0)

__global__ __launch_bounds__(512, 4) void fused_main(
    const float* __restrict__ q, const float* __restrict__ kin,
    const float* __restrict__ pos, const int* __restrict__ mask,
    const float* __restrict__ b1, const float* __restrict__ b2,
    const float* __restrict__ bo, const ushort* __restrict__ wfr,
    float* __restrict__ out)
{
  __shared__ __align__(128) char ba[TB * PITCH];  // 34KB
  __shared__ __align__(128) char bb[TB * PITCH];  // 34KB
  const char* wb = (const char*)wfr;

  const int tid = threadIdx.x;
  const int w = tid >> 6, l = tid & 63;
  const int c = l & 15, g = l >> 4;
  const int b  = blockIdx.x >> 9;           // 512 token-blocks per batch
  const int t0 = (blockIdx.x & 511) * TB;

  // B-fragment read: lane supplies B[k = ks*32 + g*8 + j][t = tf*16 + c]
  auto ldB = [&](const char* buf, int ks, int tf) -> s16x8 {
    const int t = (tf << 4) + c;
    const int col = (ks << 6) + (g << 4);
    return *(const s16x8*)(buf + t * PITCH + (col ^ ((t & 7) << 4)));
  };
  // A-fragment (weights) from packed global, 16B/lane
  auto ldA = [&](uint moff, int fi) -> s16x8 {
    return *(const s16x8*)(wb + moff + (((uint)fi << 6) | (uint)l) * 16u);
  };
  // write 4 consecutive-e bf16 values (packed lo,hi) at (e0, t)
  auto stW4 = [&](char* buf, int e0, int t, uint lo, uint hi) {
    const int byte = t * PITCH + (((uint)(e0 * 2)) ^ ((t & 7) << 4));
    *(uint2*)(buf + byte) = uint2{lo, hi};
  };

  const size_t gbase = (size_t)b * DIMX * NMX + t0 + l;

  // ---- pos + mask VMEM first: they drain concurrently with staging loads ----
  f32x4 posr[4][2];
  {
    const float* pz = pos + ((size_t)b * NMX + t0) * DIMX;
    #pragma unroll
    for (int tf = 0; tf < 4; ++tf) {
      const int t = (tf << 4) + c;
      #pragma unroll
      for (int ef = 0; ef < 2; ++ef) {
        const int e0 = (w << 5) + (ef << 4) + (g << 2);
        posr[tf][ef] =
            __builtin_nontemporal_load((const f32x4*)(pz + (size_t)t * DIMX + e0));
      }
    }
  }
  int mk[4];
  #pragma unroll
  for (int tf = 0; tf < 4; ++tf)
    mk[tf] = mask[(size_t)b * NMX + t0 + (tf << 4) + c];

  // ---- stage q -> ba, k -> bb (transposed, bf16, swizzled); nt loads ----
  #pragma unroll
  for (int j4 = 0; j4 < 4; ++j4) {
    const int d0 = (w << 5) + (j4 << 3);
    uint pq[4], pk[4];
    #pragma unroll
    for (int p = 0; p < 4; ++p) {
      const size_t o0 = gbase + (size_t)(d0 + 2 * p) * NMX;
      const size_t o1 = o0 + NMX;
      pq[p] = cvtpk(__builtin_nontemporal_load(q + o0),
                    __builtin_nontemporal_load(q + o1));
      pk[p] = cvtpk(__builtin_nontemporal_load(kin + o0),
                    __builtin_nontemporal_load(kin + o1));
    }
    const int byte = l * PITCH + ((d0 << 1) ^ ((l & 7) << 4));
    *(uint4*)(ba + byte) = uint4{pq[0], pq[1], pq[2], pq[3]};
    *(uint4*)(bb + byte) = uint4{pk[0], pk[1], pk[2], pk[3]};
  }

  __syncthreads();   // B1: tiles staged (drain covered pos/mask too)

  // pos -> bf16 (frees posr)
  uint posbf[2][4][2];
  #pragma unroll
  for (int tf = 0; tf < 4; ++tf)
    #pragma unroll
    for (int ef = 0; ef < 2; ++ef) {
      posbf[ef][tf][0] = cvtpk(posr[tf][ef][0], posr[tf][ef][1]);
      posbf[ef][tf][1] = cvtpk(posr[tf][ef][2], posr[tf][ef][3]);
    }

  // ---- phase 2 (fully merged): av = Wkv^T k;  aa = Wk^T k + (-Wq)^T q ----
  f32x4 av[2][4], aa[2][4];
  #pragma unroll
  for (int ef = 0; ef < 2; ++ef)
    #pragma unroll
    for (int tf = 0; tf < 4; ++tf) {
      av[ef][tf] = f32x4{0.f, 0.f, 0.f, 0.f};
      aa[ef][tf] = f32x4{0.f, 0.f, 0.f, 0.f};
    }
  __builtin_amdgcn_s_setprio(1);
  #pragma unroll 1
  for (int ks = 0; ks < 8; ++ks) {
    const s16x8 v0 = ldA(OFF_WKV, (ks << 4) + (w << 1));
    const s16x8 v1 = ldA(OFF_WKV, (ks << 4) + (w << 1) + 1);
    const s16x8 k0 = ldA(OFF_WK,  (ks << 4) + (w << 1));
    const s16x8 k1 = ldA(OFF_WK,  (ks << 4) + (w << 1) + 1);
    const s16x8 a0 = ldA(OFF_WQN, (ks << 4) + (w << 1));
    const s16x8 a1 = ldA(OFF_WQN, (ks << 4) + (w << 1) + 1);
    #pragma unroll
    for (int tf = 0; tf < 4; ++tf) {
      const s16x8 bk = ldB(bb, ks, tf);
      const s16x8 bq = ldB(ba, ks, tf);
      av[0][tf] = MFMA16(v0, bk, av[0][tf]);
      av[1][tf] = MFMA16(v1, bk, av[1][tf]);
      aa[0][tf] = MFMA16(k0, bk, aa[0][tf]);
      aa[1][tf] = MFMA16(k1, bk, aa[1][tf]);
      aa[0][tf] = MFMA16(a0, bq, aa[0][tf]);
      aa[1][tf] = MFMA16(a1, bq, aa[1][tf]);
    }
  }
  __builtin_amdgcn_s_setprio(0);
  // pre-fuse x-base = v + pos, pack to bf16 (av dies; register-neutral)
  uint vpbf[2][4][2];
  #pragma unroll
  for (int ef = 0; ef < 2; ++ef)
    #pragma unroll
    for (int tf = 0; tf < 4; ++tf) {
      const uint p0 = posbf[ef][tf][0], p1 = posbf[ef][tf][1];
      vpbf[ef][tf][0] = cvtpk(av[ef][tf][0] + bf_lo(p0), av[ef][tf][1] + bf_hi(p0));
      vpbf[ef][tf][1] = cvtpk(av[ef][tf][2] + bf_lo(p1), av[ef][tf][3] + bf_hi(p1));
    }
  __syncthreads();   // B2: q,k consumption done

  // ---- attn = aa + pos -> bf16 -> ba rows [w*32,+32) ----
  #pragma unroll
  for (int tf = 0; tf < 4; ++tf) {
    const int t = (tf << 4) + c;
    #pragma unroll
    for (int ef = 0; ef < 2; ++ef) {
      const int e0 = (w << 5) + (ef << 4) + (g << 2);
      const uint p0 = posbf[ef][tf][0], p1 = posbf[ef][tf][1];
      const uint lo = cvtpk(aa[ef][tf][0] + bf_lo(p0), aa[ef][tf][1] + bf_hi(p0));
      const uint hi = cvtpk(aa[ef][tf][2] + bf_lo(p1), aa[ef][tf][3] + bf_hi(p1));
      stW4(ba, e0, t, lo, hi);
    }
  }
  __syncthreads();   // B3: attn tile complete

  // ---- phase 5: h = relu(W1^T attn + b1) -> bb rows [w*16,+16) ----
  f32x4 ah[4];
  #pragma unroll
  for (int tf = 0; tf < 4; ++tf) ah[tf] = f32x4{0.f, 0.f, 0.f, 0.f};
  __builtin_amdgcn_s_setprio(1);
  #pragma unroll 2
  for (int ks = 0; ks < 8; ++ks) {
    const s16x8 a0 = ldA(OFF_W1, (ks << 3) + w);
    #pragma unroll
    for (int tf = 0; tf < 4; ++tf) {
      const s16x8 bf = ldB(ba, ks, tf);
      ah[tf] = MFMA16(a0, bf, ah[tf]);
    }
  }
  __builtin_amdgcn_s_setprio(0);
  {
    const int e0h = (w << 4) + (g << 2);
    const f32x4 b1v = *(const f32x4*)(b1 + e0h);
    #pragma unroll
    for (int tf = 0; tf < 4; ++tf) {
      const int t = (tf << 4) + c;
      const uint lo = cvtpk(fmaxf(ah[tf][0] + b1v[0], 0.f),
                            fmaxf(ah[tf][1] + b1v[1], 0.f));
      const uint hi = cvtpk(fmaxf(ah[tf][2] + b1v[2], 0.f),
                            fmaxf(ah[tf][3] + b1v[3], 0.f));
      stW4(bb, e0h, t, lo, hi);
    }
  }
  __syncthreads();   // B4: h tile complete

  // ---- phase 6: a2 = W2^T h + b2; mask; sigmoid; x = (v+pos)*sig -> ba ----
  f32x4 as_[2][4];
  #pragma unroll
  for (int ef = 0; ef < 2; ++ef)
    #pragma unroll
    for (int tf = 0; tf < 4; ++tf) as_[ef][tf] = f32x4{0.f, 0.f, 0.f, 0.f};
  __builtin_amdgcn_s_setprio(1);
  #pragma unroll
  for (int ks = 0; ks < 4; ++ks) {
    const s16x8 a0 = ldA(OFF_W2, (ks << 4) + (w << 1));
    const s16x8 a1 = ldA(OFF_W2, (ks << 4) + (w << 1) + 1);
    #pragma unroll
    for (int tf = 0; tf < 4; ++tf) {
      const s16x8 bf = ldB(bb, ks, tf);
      as_[0][tf] = MFMA16(a0, bf, as_[0][tf]);
      as_[1][tf] = MFMA16(a1, bf, as_[1][tf]);
    }
  }
  __builtin_amdgcn_s_setprio(0);
  #pragma unroll
  for (int tf = 0; tf < 4; ++tf) {
    const int t = (tf << 4) + c;
    #pragma unroll
    for (int ef = 0; ef < 2; ++ef) {
      const int e0 = (w << 5) + (ef << 4) + (g << 2);
      const f32x4 b2v = *(const f32x4*)(b2 + e0);
      float xv[4];
      #pragma unroll
      for (int i = 0; i < 4; ++i) {
        float sv = as_[ef][tf][i] + b2v[i];
        if (mk[tf] == 0) sv = -1e9f;
        const float sig = 1.f / (1.f + __expf(-sv));
        const uint vp = vpbf[ef][tf][i >> 1];
        const float xb = (i & 1) ? bf_hi(vp) : bf_lo(vp);
        xv[i] = xb * sig;
      }
      stW4(ba, e0, t, cvtpk(xv[0], xv[1]), cvtpk(xv[2], xv[3]));
    }
  }
  __syncthreads();   // B5: x tile complete

  // ---- phase 7: out = Wo^T x + bo -> (B, D, N, M); nt stores ----
  f32x4 ao[2][4];
  #pragma unroll
  for (int ef = 0; ef < 2; ++ef)
    #pragma unroll
    for (int tf = 0; tf < 4; ++tf) ao[ef][tf] = f32x4{0.f, 0.f, 0.f, 0.f};
  __builtin_amdgcn_s_setprio(1);
  #pragma unroll 2
  for (int ks = 0; ks < 8; ++ks) {
    const s16x8 a0 = ldA(OFF_WO, (ks << 4) + (w << 1));
    const s16x8 a1 = ldA(OFF_WO, (ks << 4) + (w << 1) + 1);
    #pragma unroll
    for (int tf = 0; tf < 4; ++tf) {
      const s16x8 bf = ldB(ba, ks, tf);
      ao[0][tf] = MFMA16(a0, bf, ao[0][tf]);
      ao[1][tf] = MFMA16(a1, bf, ao[1][tf]);
    }
  }
  __builtin_amdgcn_s_setprio(0);
  #pragma unroll
  for (int ef = 0; ef < 2; ++ef) {
    const int e0 = (w << 5) + (ef << 4) + (g << 2);
    const f32x4 bov = *(const f32x4*)(bo + e0);
    #pragma unroll
    for (int i = 0; i < 4; ++i) {
      float* ob = out + ((size_t)b * DIMX + e0 + i) * NMX + t0 + c;
      #pragma unroll
      for (int tf = 0; tf < 4; ++tf)
        __builtin_nontemporal_store(ao[ef][tf][i] + bov[i], ob + (tf << 4));
    }
  }
}

extern "C" void kernel_launch(void* const* d_in, const int* in_sizes, int n_in,
                              void* d_out, int out_size, void* d_ws, size_t ws_size,
                              hipStream_t stream) {
  (void)in_sizes; (void)n_in; (void)out_size; (void)ws_size;
  const float* q   = (const float*)d_in[0];
  const float* k   = (const float*)d_in[1];
  const float* pos = (const float*)d_in[2];
  const int*   msk = (const int*)d_in[3];
  const float* Wq  = (const float*)d_in[4];
  const float* Wk  = (const float*)d_in[5];
  const float* Wv  = (const float*)d_in[6];
  const float* W1  = (const float*)d_in[7];
  const float* b1  = (const float*)d_in[8];
  const float* W2  = (const float*)d_in[9];
  const float* b2  = (const float*)d_in[10];
  const float* Wo  = (const float*)d_in[11];
  const float* bo  = (const float*)d_in[12];
  float* out = (float*)d_out;
  char* ws = (char*)d_ws;
  float*  wkvf = (float*)(ws + OFF_KVF32);
  ushort* wfr  = (ushort*)ws;

  wkv_kernel<<<dim3(256), dim3(256), 0, stream>>>(Wk, Wv, wkvf);
  pack_kernel<<<dim3(640), dim3(64), 0, stream>>>(Wq, Wk, wkvf, W1, W2, Wo, wfr);
  fused_main<<<dim3(2048), dim3(512), 0, stream>>>(q, k, pos, msk, b1, b2, bo, wfr, out);
}